// Round 1
// baseline (1305.567 us; speedup 1.0000x reference)
//
#include <hip/hip_runtime.h>

#define BLK 256

// ---------------------------------------------------------------- init
__global__ void k_init(float* __restrict__ deg, float* __restrict__ acc, int N, int B) {
    int i = blockIdx.x * BLK + threadIdx.x;
    if (i < N) deg[i] = 1.0f;
    if (i < B) acc[i] = 0.0f;
}

// deg[dst] += 1 per edge
__global__ void k_deg(const int* __restrict__ dst, float* __restrict__ deg, int E) {
    int i = blockIdx.x * BLK + threadIdx.x;
    if (i < E) atomicAdd(&deg[dst[i]], 1.0f);
}

// enorm[e] = rsqrt(deg[src]) * rsqrt(deg[dst])
__global__ void k_enorm(const int* __restrict__ src, const int* __restrict__ dst,
                        const float* __restrict__ deg, float* __restrict__ enorm, int E) {
    int i = blockIdx.x * BLK + threadIdx.x;
    if (i < E) enorm[i] = rsqrtf(deg[src[i]]) * rsqrtf(deg[dst[i]]);
}

// ---------------------------------------------------------------- GEMM
// C[M][64] = A[M][K] @ W[K][64], optional ReLU applied to A on load.
// 64-row tile, 256 threads, 4x4 register blocking, A staged in K-chunks of 64.
template <int K, bool RELU>
__global__ __launch_bounds__(BLK) void k_gemm(const float* __restrict__ A,
                                              const float* __restrict__ W,
                                              float* __restrict__ C, int M) {
    __shared__ float As[64 * 64];   // 16 KB (one 64-wide K chunk)
    __shared__ float Bs[K * 64];    // <= 32 KB
    const int t = threadIdx.x;
    const int row0 = blockIdx.x * 64;

    // load W into LDS (K*64 floats = K*16 float4)
    {
        const float4* Wv = reinterpret_cast<const float4*>(W);
        float4* Bv = reinterpret_cast<float4*>(Bs);
        for (int i = t; i < K * 16; i += BLK) Bv[i] = Wv[i];
    }

    const int tx = t & 15, ty = t >> 4;
    float acc[4][4] = {};

    for (int kk = 0; kk < K; kk += 64) {
        if (kk) __syncthreads();
        // stage A[row0..row0+63][kk..kk+63] -> As[64][64]
        for (int i = t; i < 64 * 16; i += BLK) {
            int r = i >> 4, c = i & 15;
            int gr = row0 + r;
            float4 v = make_float4(0.f, 0.f, 0.f, 0.f);
            if (gr < M)
                v = *reinterpret_cast<const float4*>(A + (size_t)gr * K + kk + c * 4);
            if (RELU) {
                v.x = fmaxf(v.x, 0.f); v.y = fmaxf(v.y, 0.f);
                v.z = fmaxf(v.z, 0.f); v.w = fmaxf(v.w, 0.f);
            }
            *reinterpret_cast<float4*>(As + r * 64 + c * 4) = v;
        }
        __syncthreads();

        #pragma unroll 8
        for (int k2 = 0; k2 < 64; ++k2) {
            float a0 = As[(ty * 4 + 0) * 64 + k2];
            float a1 = As[(ty * 4 + 1) * 64 + k2];
            float a2 = As[(ty * 4 + 2) * 64 + k2];
            float a3 = As[(ty * 4 + 3) * 64 + k2];
            float4 bv = *reinterpret_cast<const float4*>(Bs + (kk + k2) * 64 + tx * 4);
            acc[0][0] = fmaf(a0, bv.x, acc[0][0]);
            acc[0][1] = fmaf(a0, bv.y, acc[0][1]);
            acc[0][2] = fmaf(a0, bv.z, acc[0][2]);
            acc[0][3] = fmaf(a0, bv.w, acc[0][3]);
            acc[1][0] = fmaf(a1, bv.x, acc[1][0]);
            acc[1][1] = fmaf(a1, bv.y, acc[1][1]);
            acc[1][2] = fmaf(a1, bv.z, acc[1][2]);
            acc[1][3] = fmaf(a1, bv.w, acc[1][3]);
            acc[2][0] = fmaf(a2, bv.x, acc[2][0]);
            acc[2][1] = fmaf(a2, bv.y, acc[2][1]);
            acc[2][2] = fmaf(a2, bv.z, acc[2][2]);
            acc[2][3] = fmaf(a2, bv.w, acc[2][3]);
            acc[3][0] = fmaf(a3, bv.x, acc[3][0]);
            acc[3][1] = fmaf(a3, bv.y, acc[3][1]);
            acc[3][2] = fmaf(a3, bv.z, acc[3][2]);
            acc[3][3] = fmaf(a3, bv.w, acc[3][3]);
        }
    }

    #pragma unroll
    for (int i = 0; i < 4; ++i) {
        int gr = row0 + ty * 4 + i;
        if (gr < M) {
            float4 v = make_float4(acc[i][0], acc[i][1], acc[i][2], acc[i][3]);
            *reinterpret_cast<float4*>(C + (size_t)gr * 64 + tx * 4) = v;
        }
    }
}

// ---------------------------------------------------------------- agg init
// agg = hw * (1/deg[n]) + bias   (self-loop term + bias; scatter adds on top)
// H == 64 assumed: 16 float4 per row.
__global__ void k_init_agg(const float4* __restrict__ hw4, const float* __restrict__ deg,
                           const float4* __restrict__ bias4, float4* __restrict__ agg4,
                           int N, int total4) {
    int i = blockIdx.x * BLK + threadIdx.x;
    if (i >= total4) return;
    int row = i >> 4;         // b*N + n
    int q = i & 15;
    int n = row % N;
    float sn = 1.0f / deg[n]; // = rsqrt(deg)^2
    float4 v = hw4[i];
    float4 bb = bias4[q];
    float4 o;
    o.x = fmaf(v.x, sn, bb.x);
    o.y = fmaf(v.y, sn, bb.y);
    o.z = fmaf(v.z, sn, bb.z);
    o.w = fmaf(v.w, sn, bb.w);
    agg4[i] = o;
}

// ---------------------------------------------------------------- scatter
// One wave per edge; lane = channel; loop over batches in registers.
__global__ void k_scatter(const float* __restrict__ hw, float* __restrict__ agg,
                          const int* __restrict__ src, const int* __restrict__ dst,
                          const float* __restrict__ enorm, int E, int N, int B) {
    int gid = blockIdx.x * BLK + threadIdx.x;
    int e = gid >> 6;
    int lane = gid & 63;
    if (e >= E) return;
    float nrm = enorm[e];
    size_t so = (size_t)src[e] * 64 + lane;
    size_t dofs = (size_t)dst[e] * 64 + lane;
    size_t stride = (size_t)N * 64;
    if (B == 8) {
        float v[8];
        #pragma unroll
        for (int b = 0; b < 8; ++b) v[b] = hw[so + b * stride];
        #pragma unroll
        for (int b = 0; b < 8; ++b) atomicAdd(&agg[dofs + b * stride], v[b] * nrm);
    } else {
        for (int b = 0; b < B; ++b)
            atomicAdd(&agg[dofs + b * stride], hw[so + b * stride] * nrm);
    }
}

// ---------------------------------------------------------------- pooled dot
// acc[b] += sum_n sum_h relu(agg2[b,n,h]) * fcw[h]   (mean & FC folded together)
__global__ void k_reduce(const float* __restrict__ agg2, const float* __restrict__ fcw,
                         float* __restrict__ acc, int N, int chunks) {
    int b = blockIdx.x / chunks;
    int chunk = blockIdx.x % chunks;
    int lane = threadIdx.x & 63;
    int w = threadIdx.x >> 6;
    int wave = chunk * (BLK >> 6) + w;
    int nwaves = chunks * (BLK >> 6);
    float fw = fcw[lane];
    float p = 0.f;
    const float* base = agg2 + (size_t)b * N * 64 + lane;
    for (int n = wave; n < N; n += nwaves)
        p += fmaxf(base[(size_t)n * 64], 0.f) * fw;
    #pragma unroll
    for (int off = 32; off; off >>= 1) p += __shfl_down(p, off, 64);
    if (lane == 0) atomicAdd(&acc[b], p);
}

__global__ void k_out(const float* __restrict__ acc, const float* __restrict__ addf,
                      const float* __restrict__ fcw, const float* __restrict__ fcb,
                      float* __restrict__ out, int N, int B, int H) {
    int b = threadIdx.x;
    if (b < B) out[b] = acc[b] / (float)N + addf[b] * fcw[H] + fcb[0];
}

// ---------------------------------------------------------------- launch
extern "C" void kernel_launch(void* const* d_in, const int* in_sizes, int n_in,
                              void* d_out, int out_size, void* d_ws, size_t ws_size,
                              hipStream_t stream) {
    const float* x    = (const float*)d_in[0];
    const float* addf = (const float*)d_in[1];
    const int*   ei   = (const int*)d_in[2];
    const float* W1   = (const float*)d_in[3];
    const float* b1   = (const float*)d_in[4];
    const float* W2   = (const float*)d_in[5];
    const float* b2   = (const float*)d_in[6];
    const float* fcw  = (const float*)d_in[7];
    const float* fcb  = (const float*)d_in[8];
    float* out = (float*)d_out;

    const int B  = in_sizes[1];            // 8
    const int H  = in_sizes[4];            // 64
    const int IN = in_sizes[3] / H;        // 128
    const int E  = in_sizes[2] / 2;        // 320000
    const int N  = in_sizes[0] / (B * IN); // 20000
    const int* src = ei;
    const int* dst = ei + E;

    const int M = B * N;                   // 160000 rows
    float* ws = (float*)d_ws;
    size_t bufsz = (size_t)M * H;          // 10.24M floats
    float* bufA  = ws;                     // hw1, then hw2
    float* bufB  = ws + bufsz;             // agg1, then agg2
    float* deg   = bufB + bufsz;
    float* enorm = deg + ((N + 3) & ~3);
    float* acc   = enorm + ((E + 3) & ~3);

    const int total4 = M * (H / 4);        // float4 count of one buffer

    // degree + norms
    k_init<<<dim3((N + BLK - 1) / BLK), dim3(BLK), 0, stream>>>(deg, acc, N, B);
    k_deg<<<dim3((E + BLK - 1) / BLK), dim3(BLK), 0, stream>>>(dst, deg, E);
    k_enorm<<<dim3((E + BLK - 1) / BLK), dim3(BLK), 0, stream>>>(src, dst, deg, enorm, E);

    // layer 1: hw1 = x @ W1  -> bufA
    k_gemm<128, false><<<dim3((M + 63) / 64), dim3(BLK), 0, stream>>>(x, W1, bufA, M);
    // agg1 = hw1/deg + b1 -> bufB
    k_init_agg<<<dim3((total4 + BLK - 1) / BLK), dim3(BLK), 0, stream>>>(
        (const float4*)bufA, deg, (const float4*)b1, (float4*)bufB, N, total4);
    // agg1 += scatter(hw1 * enorm)
    k_scatter<<<dim3(E / 4), dim3(BLK), 0, stream>>>(bufA, bufB, src, dst, enorm, E, N, B);

    // layer 2: hw2 = relu(agg1) @ W2 -> bufA
    k_gemm<64, true><<<dim3((M + 63) / 64), dim3(BLK), 0, stream>>>(bufB, W2, bufA, M);
    // agg2 = hw2/deg + b2 -> bufB
    k_init_agg<<<dim3((total4 + BLK - 1) / BLK), dim3(BLK), 0, stream>>>(
        (const float4*)bufA, deg, (const float4*)b2, (float4*)bufB, N, total4);
    // agg2 += scatter(hw2 * enorm)
    k_scatter<<<dim3(E / 4), dim3(BLK), 0, stream>>>(bufA, bufB, src, dst, enorm, E, N, B);

    // pooled dot + final linear
    const int chunks = 64;
    k_reduce<<<dim3(B * chunks), dim3(BLK), 0, stream>>>(bufB, fcw, acc, N, chunks);
    k_out<<<dim3(1), dim3(64), 0, stream>>>(acc, addf, fcw, fcb, out, N, B, H);
}

// Round 2
// 485.857 us; speedup vs baseline: 2.6871x; 2.6871x over previous
//
#include <hip/hip_runtime.h>

#define BLK 256

// ---------------------------------------------------------------- zero
__global__ void k_zero(int* __restrict__ cnt, float* __restrict__ acc, int N, int B) {
    int i = blockIdx.x * BLK + threadIdx.x;
    if (i < N) cnt[i] = 0;
    if (i < B) acc[i] = 0.0f;
}

// cnt[dst] += 1 per edge (int in-degree)
__global__ void k_count(const int* __restrict__ dst, int* __restrict__ cnt, int E) {
    int i = blockIdx.x * BLK + threadIdx.x;
    if (i < E) atomicAdd(&cnt[dst[i]], 1);
}

// ---------------------------------------------------------------- scan (exclusive, 2-level)
__global__ void k_scan1(const int* __restrict__ cnt, int* __restrict__ rs,
                        int* __restrict__ bsum, int N) {
    __shared__ int s[BLK];
    int i = blockIdx.x * BLK + threadIdx.x;
    int v = (i < N) ? cnt[i] : 0;
    s[threadIdx.x] = v;
    __syncthreads();
    for (int off = 1; off < BLK; off <<= 1) {
        int t = (threadIdx.x >= off) ? s[threadIdx.x - off] : 0;
        __syncthreads();
        s[threadIdx.x] += t;
        __syncthreads();
    }
    if (i < N) rs[i] = s[threadIdx.x] - v;  // exclusive within block
    if (threadIdx.x == BLK - 1) bsum[blockIdx.x] = s[BLK - 1];
}

__global__ void k_scan2(int* __restrict__ bsum, int nb) {
    if (threadIdx.x == 0) {
        int r = 0;
        for (int i = 0; i < nb; ++i) { int t = bsum[i]; bsum[i] = r; r += t; }
    }
}

__global__ void k_scan3(int* __restrict__ rs, int* __restrict__ cur,
                        const int* __restrict__ bsum, int N) {
    int i = blockIdx.x * BLK + threadIdx.x;
    if (i < N) {
        int v = rs[i] + bsum[blockIdx.x];
        rs[i] = v;
        cur[i] = v;
    }
}

// ---------------------------------------------------------------- CSR fill
// csr_src[p] = src, csr_w[p] = rsqrt((1+deg_s)*(1+deg_d))
__global__ void k_fill(const int* __restrict__ src, const int* __restrict__ dst,
                       const int* __restrict__ cnt, int* __restrict__ cur,
                       int* __restrict__ csrc, float* __restrict__ cw, int E) {
    int e = blockIdx.x * BLK + threadIdx.x;
    if (e >= E) return;
    int d = dst[e], s = src[e];
    int p = atomicAdd(&cur[d], 1);
    csrc[p] = s;
    cw[p] = rsqrtf((1.0f + (float)cnt[s]) * (1.0f + (float)cnt[d]));
}

// ---------------------------------------------------------------- GEMM
// C[M][64] = A[M][K] @ W[K][64]; node-major permutation optional on A rows and C rows.
// logical row gr = b*N + n; node-major offset = (n*B + b).
template <int K, bool RELU, bool PIN, bool POUT>
__global__ __launch_bounds__(BLK) void k_gemm(const float* __restrict__ A,
                                              const float* __restrict__ W,
                                              float* __restrict__ C, int M, int N, int B) {
    __shared__ float As[64 * 64];
    __shared__ float Bs[K * 64];
    const int t = threadIdx.x;
    const int row0 = blockIdx.x * 64;

    {
        const float4* Wv = reinterpret_cast<const float4*>(W);
        float4* Bv = reinterpret_cast<float4*>(Bs);
        for (int i = t; i < K * 16; i += BLK) Bv[i] = Wv[i];
    }

    const int tx = t & 15, ty = t >> 4;
    float acc[4][4] = {};

    for (int kk = 0; kk < K; kk += 64) {
        if (kk) __syncthreads();
        for (int i = t; i < 64 * 16; i += BLK) {
            int r = i >> 4, c = i & 15;
            int gr = row0 + r;
            float4 v = make_float4(0.f, 0.f, 0.f, 0.f);
            if (gr < M) {
                size_t ra = PIN ? ((size_t)(gr % N) * B + gr / N) : (size_t)gr;
                v = *reinterpret_cast<const float4*>(A + ra * K + kk + c * 4);
            }
            if (RELU) {
                v.x = fmaxf(v.x, 0.f); v.y = fmaxf(v.y, 0.f);
                v.z = fmaxf(v.z, 0.f); v.w = fmaxf(v.w, 0.f);
            }
            *reinterpret_cast<float4*>(As + r * 64 + c * 4) = v;
        }
        __syncthreads();

        #pragma unroll 8
        for (int k2 = 0; k2 < 64; ++k2) {
            float a0 = As[(ty * 4 + 0) * 64 + k2];
            float a1 = As[(ty * 4 + 1) * 64 + k2];
            float a2 = As[(ty * 4 + 2) * 64 + k2];
            float a3 = As[(ty * 4 + 3) * 64 + k2];
            float4 bv = *reinterpret_cast<const float4*>(Bs + (kk + k2) * 64 + tx * 4);
            acc[0][0] = fmaf(a0, bv.x, acc[0][0]);
            acc[0][1] = fmaf(a0, bv.y, acc[0][1]);
            acc[0][2] = fmaf(a0, bv.z, acc[0][2]);
            acc[0][3] = fmaf(a0, bv.w, acc[0][3]);
            acc[1][0] = fmaf(a1, bv.x, acc[1][0]);
            acc[1][1] = fmaf(a1, bv.y, acc[1][1]);
            acc[1][2] = fmaf(a1, bv.z, acc[1][2]);
            acc[1][3] = fmaf(a1, bv.w, acc[1][3]);
            acc[2][0] = fmaf(a2, bv.x, acc[2][0]);
            acc[2][1] = fmaf(a2, bv.y, acc[2][1]);
            acc[2][2] = fmaf(a2, bv.z, acc[2][2]);
            acc[2][3] = fmaf(a2, bv.w, acc[2][3]);
            acc[3][0] = fmaf(a3, bv.x, acc[3][0]);
            acc[3][1] = fmaf(a3, bv.y, acc[3][1]);
            acc[3][2] = fmaf(a3, bv.z, acc[3][2]);
            acc[3][3] = fmaf(a3, bv.w, acc[3][3]);
        }
    }

    #pragma unroll
    for (int i = 0; i < 4; ++i) {
        int gr = row0 + ty * 4 + i;
        if (gr < M) {
            size_t rc = POUT ? ((size_t)(gr % N) * B + gr / N) : (size_t)gr;
            float4 v = make_float4(acc[i][0], acc[i][1], acc[i][2], acc[i][3]);
            *reinterpret_cast<float4*>(C + rc * 64 + tx * 4) = v;
        }
    }
}

// ---------------------------------------------------------------- gather aggregate
// One block per dst node; blockDim = B*64. Node-major layout [N][B][64].
// agg[n] = sum_e w_e * hw[src_e] + hw[n] * selfnorm + bias
__global__ __launch_bounds__(512) void k_gather(const float* __restrict__ hw,
                                                const int* __restrict__ rs,
                                                const int* __restrict__ cnt,
                                                const int* __restrict__ csrc,
                                                const float* __restrict__ cw,
                                                const float* __restrict__ bias,
                                                float* __restrict__ agg, int BH) {
    int n = blockIdx.x;
    int tid = threadIdx.x;
    int lane = tid & 63;
    int beg = rs[n];
    int deg = cnt[n];
    float self = 1.0f / (1.0f + (float)deg);
    float a = fmaf(hw[(size_t)n * BH + tid], self, bias[lane]);
    int i = 0;
    for (; i + 2 <= deg; i += 2) {
        int s0 = csrc[beg + i], s1 = csrc[beg + i + 1];
        float w0 = cw[beg + i], w1 = cw[beg + i + 1];
        float v0 = hw[(size_t)s0 * BH + tid];
        float v1 = hw[(size_t)s1 * BH + tid];
        a = fmaf(w0, v0, a);
        a = fmaf(w1, v1, a);
    }
    if (i < deg) {
        int s0 = csrc[beg + i];
        a = fmaf(cw[beg + i], hw[(size_t)s0 * BH + tid], a);
    }
    agg[(size_t)n * BH + tid] = a;
}

// ---------------------------------------------------------------- pooled dot
// acc[b] += sum_n sum_h relu(agg2[n,b,h]) * fcw[h]  (node-major layout)
__global__ void k_reduce(const float* __restrict__ agg2, const float* __restrict__ fcw,
                         float* __restrict__ acc, int N, int B, int chunks) {
    int b = blockIdx.x / chunks;
    int chunk = blockIdx.x % chunks;
    int lane = threadIdx.x & 63;
    int w = threadIdx.x >> 6;
    int wave = chunk * (BLK >> 6) + w;
    int nwaves = chunks * (BLK >> 6);
    float fw = fcw[lane];
    float p = 0.f;
    const float* base = agg2 + (size_t)b * 64 + lane;
    size_t stride = (size_t)B * 64;
    for (int n = wave; n < N; n += nwaves)
        p += fmaxf(base[(size_t)n * stride], 0.f) * fw;
    #pragma unroll
    for (int off = 32; off; off >>= 1) p += __shfl_down(p, off, 64);
    if (lane == 0) atomicAdd(&acc[b], p);
}

__global__ void k_out(const float* __restrict__ acc, const float* __restrict__ addf,
                      const float* __restrict__ fcw, const float* __restrict__ fcb,
                      float* __restrict__ out, int N, int B, int H) {
    int b = threadIdx.x;
    if (b < B) out[b] = acc[b] / (float)N + addf[b] * fcw[H] + fcb[0];
}

// ---------------------------------------------------------------- launch
extern "C" void kernel_launch(void* const* d_in, const int* in_sizes, int n_in,
                              void* d_out, int out_size, void* d_ws, size_t ws_size,
                              hipStream_t stream) {
    const float* x    = (const float*)d_in[0];
    const float* addf = (const float*)d_in[1];
    const int*   ei   = (const int*)d_in[2];
    const float* W1   = (const float*)d_in[3];
    const float* b1   = (const float*)d_in[4];
    const float* W2   = (const float*)d_in[5];
    const float* b2   = (const float*)d_in[6];
    const float* fcw  = (const float*)d_in[7];
    const float* fcb  = (const float*)d_in[8];
    float* out = (float*)d_out;

    const int B  = in_sizes[1];            // 8
    const int H  = in_sizes[4];            // 64
    const int IN = in_sizes[3] / H;        // 128
    const int E  = in_sizes[2] / 2;        // 320000
    const int N  = in_sizes[0] / (B * IN); // 20000
    const int* src = ei;
    const int* dst = ei + E;

    const int M  = B * N;                  // 160000 rows
    const int BH = B * H;                  // 512

    float* ws = (float*)d_ws;
    size_t bufsz = (size_t)M * H;          // 10.24M floats
    float* bufA  = ws;                     // hw (node-major)
    float* bufB  = ws + bufsz;             // agg (node-major)
    int*   cnt   = (int*)(bufB + bufsz);
    int*   rs    = cnt + N;
    int*   cur   = rs + N;
    int*   csrc  = cur + N;
    float* cw    = (float*)(csrc + E);
    int*   bsum  = (int*)(cw + E);
    float* acc   = (float*)(bsum + 256);

    const int nbN = (N + BLK - 1) / BLK;
    const int nbE = (E + BLK - 1) / BLK;

    // CSR build
    k_zero<<<dim3(nbN), dim3(BLK), 0, stream>>>(cnt, acc, N, B);
    k_count<<<dim3(nbE), dim3(BLK), 0, stream>>>(dst, cnt, E);
    k_scan1<<<dim3(nbN), dim3(BLK), 0, stream>>>(cnt, rs, bsum, N);
    k_scan2<<<dim3(1), dim3(64), 0, stream>>>(bsum, nbN);
    k_scan3<<<dim3(nbN), dim3(BLK), 0, stream>>>(rs, cur, bsum, N);
    k_fill<<<dim3(nbE), dim3(BLK), 0, stream>>>(src, dst, cnt, cur, csrc, cw, E);

    // layer 1: hw1 = x @ W1 -> bufA (node-major)
    k_gemm<128, false, false, true><<<dim3((M + 63) / 64), dim3(BLK), 0, stream>>>(
        x, W1, bufA, M, N, B);
    // agg1 = gather(hw1) + self + b1 -> bufB
    k_gather<<<dim3(N), dim3(BH), 0, stream>>>(bufA, rs, cnt, csrc, cw, b1, bufB, BH);

    // layer 2: hw2 = relu(agg1) @ W2 -> bufA (node-major in and out)
    k_gemm<64, true, true, true><<<dim3((M + 63) / 64), dim3(BLK), 0, stream>>>(
        bufB, W2, bufA, M, N, B);
    // agg2 = gather(hw2) + self + b2 -> bufB
    k_gather<<<dim3(N), dim3(BH), 0, stream>>>(bufA, rs, cnt, csrc, cw, b2, bufB, BH);

    // pooled dot + final linear
    const int chunks = 64;
    k_reduce<<<dim3(B * chunks), dim3(BLK), 0, stream>>>(bufB, fcw, acc, N, B, chunks);
    k_out<<<dim3(1), dim3(64), 0, stream>>>(acc, addf, fcw, fcb, out, N, B, H);
}